// Round 15
// baseline (292.446 us; speedup 1.0000x reference)
//
#include <hip/hip_runtime.h>
#include <hip/hip_bf16.h>

#define B_N 32
#define SX 2048
#define SY 512
#define DIM 1024
#define NTOK 2
#define DN 128
#define ODIM 1024
#define BM 64
#define TROWS 16
#define NTL 4   // row-tiles per block

typedef __bf16 bf16;
typedef __bf16 bf16x8 __attribute__((ext_vector_type(8)));
typedef __bf16 bf16x4 __attribute__((ext_vector_type(4)));
typedef float f32x4 __attribute__((ext_vector_type(4)));

typedef __attribute__((address_space(3))) unsigned char lds_u8;
typedef const __attribute__((address_space(1))) unsigned char glb_u8;

__device__ __forceinline__ f32x4 mfma16(bf16x8 a, bf16x8 b, f32x4 c) {
  return __builtin_amdgcn_mfma_f32_16x16x32_bf16(a, b, c, 0, 0, 0);
}
__device__ __forceinline__ void gll16(const void* g, void* l) {
  __builtin_amdgcn_global_load_lds((glb_u8*)g, (lds_u8*)l, 16, 0, 0);
}

// Convert weights fp32 -> bf16 once per call.
__global__ __launch_bounds__(256) void prep_kernel(const float* __restrict__ Wd,
                                                   const float* __restrict__ Wu,
                                                   bf16* __restrict__ wdb,
                                                   bf16* __restrict__ wub) {
  int i = blockIdx.x * 256 + threadIdx.x;
  if (i < DN * DIM) {
    wdb[i] = (bf16)Wd[i];
    wub[i] = (bf16)Wu[i];
  }
}

// tokens kernel: only needed when gate != 0 (bench has gate == 0).
__global__ __launch_bounds__(256) void tokens_kernel(const float* __restrict__ y,
                                                     const float* __restrict__ lat,
                                                     const float* __restrict__ gate,
                                                     float* __restrict__ tokens) {
  if (gate[0] == 0.0f) return;
  __shared__ float s_lat[NTOK][DIM];
  __shared__ float s_sc[NTOK][SY];
  int b = blockIdx.x;
  int tid = threadIdx.x, wave = tid >> 6, lane = tid & 63;
  const float* yb = y + (size_t)b * SY * DIM;
  for (int i = tid; i < NTOK * DIM; i += 256) ((float*)s_lat)[i] = lat[i];
  __syncthreads();
  for (int s = wave * 128; s < wave * 128 + 128; ++s) {
    const float* yr = yb + (size_t)s * DIM;
    float d0 = 0.f, d1 = 0.f;
#pragma unroll
    for (int i = 0; i < 4; ++i) {
      f32x4 v = *(const f32x4*)(yr + lane * 4 + i * 256);
      f32x4 l0 = *(const f32x4*)(&s_lat[0][lane * 4 + i * 256]);
      f32x4 l1 = *(const f32x4*)(&s_lat[1][lane * 4 + i * 256]);
      d0 += v[0] * l0[0] + v[1] * l0[1] + v[2] * l0[2] + v[3] * l0[3];
      d1 += v[0] * l1[0] + v[1] * l1[1] + v[2] * l1[2] + v[3] * l1[3];
    }
#pragma unroll
    for (int off = 32; off > 0; off >>= 1) {
      d0 += __shfl_xor(d0, off);
      d1 += __shfl_xor(d1, off);
    }
    if (lane == 0) { s_sc[0][s] = d0; s_sc[1][s] = d1; }
  }
  __syncthreads();
  if (wave < 2) {
    float m = -3.4e38f;
    for (int s = lane; s < SY; s += 64) m = fmaxf(m, s_sc[wave][s]);
#pragma unroll
    for (int off = 32; off > 0; off >>= 1) m = fmaxf(m, __shfl_xor(m, off));
    float sum = 0.f;
    for (int s = lane; s < SY; s += 64) {
      float e = expf(s_sc[wave][s] - m);
      s_sc[wave][s] = e;
      sum += e;
    }
#pragma unroll
    for (int off = 32; off > 0; off >>= 1) sum += __shfl_xor(sum, off);
    float inv = 1.f / sum;
    for (int s = lane; s < SY; s += 64) s_sc[wave][s] *= inv;
  }
  __syncthreads();
  float a0[4] = {0.f, 0.f, 0.f, 0.f}, a1[4] = {0.f, 0.f, 0.f, 0.f};
  for (int s = 0; s < SY; ++s) {
    float p0 = s_sc[0][s], p1 = s_sc[1][s];
    const float* yr = yb + (size_t)s * DIM;
#pragma unroll
    for (int i = 0; i < 4; ++i) {
      float v = yr[tid + i * 256];
      a0[i] += p0 * v;
      a1[i] += p1 * v;
    }
  }
  float* tb = tokens + (size_t)b * NTOK * DIM;
#pragma unroll
  for (int i = 0; i < 4; ++i) {
    tb[tid + i * 256] = s_lat[0][tid + i * 256] + a0[i];
    tb[DIM + tid + i * 256] = s_lat[1][tid + i * 256] + a1[i];
  }
}

// gate != 0 slow path only: xp = x + softmax(x.tok)*tok*gate, into d_out.
__global__ __launch_bounds__(256) void xprime_kernel(const float* __restrict__ x,
                                                     const float* __restrict__ gate,
                                                     const float* __restrict__ tokens,
                                                     float* __restrict__ xp) {
  float g = gate[0];
  if (g == 0.0f) return;
  __shared__ float s_tok[NTOK][DIM];
  __shared__ float s_c[BM][2];
  int tid = threadIdx.x, w = tid >> 6, lane = tid & 63;
  size_t m0 = (size_t)blockIdx.x * BM;
  int b = (int)(m0 / SX);
  const float* xb = x + m0 * DIM;
  const float* tokb = tokens + (size_t)b * NTOK * DIM;
  for (int i = tid; i < NTOK * DIM; i += 256) ((float*)s_tok)[i] = tokb[i];
  __syncthreads();
  for (int i = 0; i < 16; ++i) {
    int r = w * 16 + i;
    const float* xrow = xb + (size_t)r * DIM;
    float d0 = 0.f, d1 = 0.f;
#pragma unroll
    for (int c = 0; c < 4; ++c) {
      f32x4 v = *(const f32x4*)(xrow + lane * 4 + c * 256);
      f32x4 t0 = *(const f32x4*)(&s_tok[0][lane * 4 + c * 256]);
      f32x4 t1 = *(const f32x4*)(&s_tok[1][lane * 4 + c * 256]);
      d0 += v[0] * t0[0] + v[1] * t0[1] + v[2] * t0[2] + v[3] * t0[3];
      d1 += v[0] * t1[0] + v[1] * t1[1] + v[2] * t1[2] + v[3] * t1[3];
    }
#pragma unroll
    for (int off = 32; off > 0; off >>= 1) {
      d0 += __shfl_xor(d0, off);
      d1 += __shfl_xor(d1, off);
    }
    if (lane == 0) {
      float mm = fmaxf(d0, d1);
      float e0 = expf(d0 - mm), e1 = expf(d1 - mm);
      float inv = g / (e0 + e1);
      s_c[r][0] = e0 * inv;
      s_c[r][1] = e1 * inv;
    }
  }
  __syncthreads();
  float* xpb = xp + m0 * DIM;
  for (int r = w * 16; r < w * 16 + 16; ++r) {
    float c0 = s_c[r][0], c1 = s_c[r][1];
#pragma unroll
    for (int c = 0; c < 4; ++c) {
      f32x4 v = *(const f32x4*)(xb + (size_t)r * DIM + lane * 4 + c * 256);
      f32x4 t0 = *(const f32x4*)(&s_tok[0][lane * 4 + c * 256]);
      f32x4 t1 = *(const f32x4*)(&s_tok[1][lane * 4 + c * 256]);
      f32x4 o;
#pragma unroll
      for (int j = 0; j < 4; ++j) o[j] = v[j] + c0 * t0[j] + c1 * t1[j];
      *(f32x4*)(xpb + (size_t)r * DIM + lane * 4 + c * 256) = o;
    }
  }
}

// Row-tiled fused kernel (DRAM-sequential reads, in-stream writes).
// Block = 64 rows = 4 row-tiles of 16. Per tile:
//   STAGE(t+1): 16 FULL rows (64KB) via gll, fully sequential addresses
//               (each wave stages 2 whole rows; pre-swizzled source).
//   vmcnt(8) -> barrier -> GEMM1(t): Wd entirely in VGPRs (128), x from LDS,
//   zero VMEM inside -> Z exchange (8KB LDS) -> barrier ->
//   GEMM2(t) + 64KB stores (strips back-to-back: full 128B lines).
// Reads and writes interleave at 16-row granularity like a copy kernel.
// R15 fix: STAGE(0) prologue was missing in R14 (tile 0 read poison LDS).
__global__ __launch_bounds__(512) void main_kernel(const float* __restrict__ x,
                                                   const float* __restrict__ gate,
                                                   const float* __restrict__ xp,
                                                   const bf16* __restrict__ wdb,
                                                   const bf16* __restrict__ wub,
                                                   float* __restrict__ out) {
  // [0,131072): x ring 2 x [16 rows][4096B] fp32, swizzled ((r&7)<<5 on 32B)
  // [131072,139264): Z tile bf16 [16][128], swizzled
  __shared__ __align__(16) char smem[139264];

  int tid = threadIdx.x, w = tid >> 6, l = tid & 63;
  int lq = l >> 4, lr = l & 15;
  size_t m0 = (size_t)blockIdx.x * BM;
  float g = gate[0];
  const float* xb = ((g != 0.f) ? xp : x) + m0 * DIM;

  // ---- Wd preload: full K for this wave's 16 dn rows (128 VGPR) ----
  bf16x8 wdr[32];
  {
    const bf16* wdp = wdb + (size_t)(w * 16 + lr) * DIM + lq * 8;
#pragma unroll
    for (int kc = 0; kc < 32; ++kc) wdr[kc] = *(const bf16x8*)(wdp + kc * 32);
  }

  // ---- gll sources: wave stages tile-local rows {w*2, w*2+1} ----
  // LDS[r][off] = x[r][off ^ ((r&7)<<5)]; swizzle < 1024 so it only permutes
  // the lane*16 part -> source stays within the same sequential 1KB chunk.
  int r0 = w * 2, r1 = w * 2 + 1;
  const char* xs0 = (const char*)xb + (size_t)r0 * 4096 + ((l * 16) ^ ((r0 & 7) << 5));
  const char* xs1 = (const char*)xb + (size_t)r1 * 4096 + ((l * 16) ^ ((r1 & 7) << 5));

  auto STAGE = [&](int t) {
    char* buf = smem + (t & 1) * 65536;
    const char* s0 = xs0 + (size_t)t * 65536;  // 16 rows * 4KB per tile
    const char* s1 = xs1 + (size_t)t * 65536;
#pragma unroll
    for (int c = 0; c < 4; ++c) gll16(s0 + c * 1024, buf + r0 * 4096 + c * 1024);
#pragma unroll
    for (int c = 0; c < 4; ++c) gll16(s1 + c * 1024, buf + r1 * 4096 + c * 1024);
  };

  char* zls = smem + 131072;
  float* ob = out + m0 * ODIM;

  STAGE(0);  // <-- R15 fix: prologue stage of tile 0

#pragma unroll
  for (int t = 0; t < NTL; ++t) {
    if (t + 1 < NTL) {
      STAGE(t + 1);
      asm volatile("s_waitcnt vmcnt(8)" ::: "memory");  // tile t landed; t+1 in flight
    } else {
      asm volatile("s_waitcnt vmcnt(0)" ::: "memory");
    }
    __builtin_amdgcn_sched_barrier(0);
    __builtin_amdgcn_s_barrier();

    // ---- GEMM1(t): D[dn16][row16], Wd from regs, x from LDS ----
    const char* xt = smem + (t & 1) * 65536;
    f32x4 acc = {};
    __builtin_amdgcn_s_setprio(1);
#pragma unroll
    for (int kc = 0; kc < 32; ++kc) {
      int sw = (lr & 7) << 5;
      int kb = kc * 128 + lq * 32;
      f32x4 a0 = *(const f32x4*)(xt + lr * 4096 + (kb ^ sw));
      f32x4 a1 = *(const f32x4*)(xt + lr * 4096 + ((kb ^ sw) + 16));
      bf16x8 xf;
#pragma unroll
      for (int j = 0; j < 4; ++j) {
        xf[j] = (bf16)a0[j];
        xf[4 + j] = (bf16)a1[j];
      }
      acc = mfma16(wdr[kc], xf, acc);
    }
    __builtin_amdgcn_s_setprio(0);

    // ---- ReLU -> Z[16][128] bf16 swizzled (lane: row=lr, dn=w*16+lq*4+r) ----
    {
      int dn = w * 16 + lq * 4;
      bf16x4 pk;
#pragma unroll
      for (int r = 0; r < 4; ++r) pk[r] = (bf16)fmaxf(acc[r], 0.f);
      *(bf16x4*)(zls + lr * (DN * 2) + ((dn * 2) ^ ((lr & 7) << 4))) = pk;
    }
    asm volatile("s_waitcnt lgkmcnt(0)" ::: "memory");
    __builtin_amdgcn_sched_barrier(0);
    __builtin_amdgcn_s_barrier();

    // ---- GEMM2(t): wave w -> out cols [w*128,+128), rows = tile's 16 ----
    bf16x8 zF[4];
#pragma unroll
    for (int kt = 0; kt < 4; ++kt)
      zF[kt] = *(const bf16x8*)(zls + lr * (DN * 2) +
                                (((kt * 32 + lq * 8) * 2) ^ ((lr & 7) << 4)));
    float* obt = ob + (size_t)t * TROWS * ODIM;
#pragma unroll
    for (int s = 0; s < 8; ++s) {
      int base = w * 128 + s * 16;
      bf16x8 wu[4];
#pragma unroll
      for (int kt = 0; kt < 4; ++kt)
        wu[kt] = *(const bf16x8*)(wub + (size_t)(base + lr) * DN + kt * 32 + lq * 8);
      f32x4 a2 = {};
#pragma unroll
      for (int kt = 0; kt < 4; ++kt) a2 = mfma16(wu[kt], zF[kt], a2);
      *(f32x4*)(obt + (size_t)lr * ODIM + base + lq * 4) = a2;
    }
  }
}

extern "C" void kernel_launch(void* const* d_in, const int* in_sizes, int n_in,
                              void* d_out, int out_size, void* d_ws, size_t ws_size,
                              hipStream_t stream) {
  const float* x = (const float*)d_in[0];
  const float* y = (const float*)d_in[1];
  const float* lat = (const float*)d_in[2];
  const float* gate = (const float*)d_in[3];
  const float* Wd = (const float*)d_in[4];
  const float* Wu = (const float*)d_in[5];
  float* out = (float*)d_out;
  char* ws = (char*)d_ws;

  float* tokens = (float*)ws;              // 262144 B
  bf16* wdb = (bf16*)(ws + 262144);        // 262144 B
  bf16* wub = (bf16*)(ws + 524288);        // 262144 B

  prep_kernel<<<(DN * DIM + 255) / 256, 256, 0, stream>>>(Wd, Wu, wdb, wub);
  tokens_kernel<<<B_N, 256, 0, stream>>>(y, lat, gate, tokens);
  // gate!=0 only: writes x' into d_out; main reads each tile's rows before
  // overwriting them (tile t's stores touch only rows already fully staged).
  xprime_kernel<<<(B_N * SX) / BM, 256, 0, stream>>>(x, gate, tokens, out);
  main_kernel<<<(B_N * SX) / BM, 512, 0, stream>>>(x, gate, out, wdb, wub, out);
}

// Round 16
// 144.769 us; speedup vs baseline: 2.0201x; 2.0201x over previous
//
#include <hip/hip_runtime.h>
#include <hip/hip_bf16.h>

#define B_N 32
#define SX 2048
#define SY 512
#define DIM 1024
#define NTOK 2
#define DN 128
#define ODIM 1024
#define BM 64
#define BK 64
#define NT 16   // K tiles
#define RING 4

typedef __bf16 bf16;
typedef __bf16 bf16x8 __attribute__((ext_vector_type(8)));
typedef __bf16 bf16x4 __attribute__((ext_vector_type(4)));
typedef float f32x4 __attribute__((ext_vector_type(4)));

typedef __attribute__((address_space(3))) unsigned char lds_u8;
typedef const __attribute__((address_space(1))) unsigned char glb_u8;

__device__ __forceinline__ f32x4 mfma16(bf16x8 a, bf16x8 b, f32x4 c) {
  return __builtin_amdgcn_mfma_f32_16x16x32_bf16(a, b, c, 0, 0, 0);
}
__device__ __forceinline__ void gll16(const void* g, void* l) {
  __builtin_amdgcn_global_load_lds((glb_u8*)g, (lds_u8*)l, 16, 0, 0);
}

// Convert weights fp32 -> bf16 once per call.
__global__ __launch_bounds__(256) void prep_kernel(const float* __restrict__ Wd,
                                                   const float* __restrict__ Wu,
                                                   bf16* __restrict__ wdb,
                                                   bf16* __restrict__ wub) {
  int i = blockIdx.x * 256 + threadIdx.x;
  if (i < DN * DIM) {
    wdb[i] = (bf16)Wd[i];
    wub[i] = (bf16)Wu[i];
  }
}

// tokens kernel: only needed when gate != 0 (bench has gate == 0).
__global__ __launch_bounds__(256) void tokens_kernel(const float* __restrict__ y,
                                                     const float* __restrict__ lat,
                                                     const float* __restrict__ gate,
                                                     float* __restrict__ tokens) {
  if (gate[0] == 0.0f) return;
  __shared__ float s_lat[NTOK][DIM];
  __shared__ float s_sc[NTOK][SY];
  int b = blockIdx.x;
  int tid = threadIdx.x, wave = tid >> 6, lane = tid & 63;
  const float* yb = y + (size_t)b * SY * DIM;
  for (int i = tid; i < NTOK * DIM; i += 256) ((float*)s_lat)[i] = lat[i];
  __syncthreads();
  for (int s = wave * 128; s < wave * 128 + 128; ++s) {
    const float* yr = yb + (size_t)s * DIM;
    float d0 = 0.f, d1 = 0.f;
#pragma unroll
    for (int i = 0; i < 4; ++i) {
      f32x4 v = *(const f32x4*)(yr + lane * 4 + i * 256);
      f32x4 l0 = *(const f32x4*)(&s_lat[0][lane * 4 + i * 256]);
      f32x4 l1 = *(const f32x4*)(&s_lat[1][lane * 4 + i * 256]);
      d0 += v[0] * l0[0] + v[1] * l0[1] + v[2] * l0[2] + v[3] * l0[3];
      d1 += v[0] * l1[0] + v[1] * l1[1] + v[2] * l1[2] + v[3] * l1[3];
    }
#pragma unroll
    for (int off = 32; off > 0; off >>= 1) {
      d0 += __shfl_xor(d0, off);
      d1 += __shfl_xor(d1, off);
    }
    if (lane == 0) { s_sc[0][s] = d0; s_sc[1][s] = d1; }
  }
  __syncthreads();
  if (wave < 2) {
    float m = -3.4e38f;
    for (int s = lane; s < SY; s += 64) m = fmaxf(m, s_sc[wave][s]);
#pragma unroll
    for (int off = 32; off > 0; off >>= 1) m = fmaxf(m, __shfl_xor(m, off));
    float sum = 0.f;
    for (int s = lane; s < SY; s += 64) {
      float e = expf(s_sc[wave][s] - m);
      s_sc[wave][s] = e;
      sum += e;
    }
#pragma unroll
    for (int off = 32; off > 0; off >>= 1) sum += __shfl_xor(sum, off);
    float inv = 1.f / sum;
    for (int s = lane; s < SY; s += 64) s_sc[wave][s] *= inv;
  }
  __syncthreads();
  float a0[4] = {0.f, 0.f, 0.f, 0.f}, a1[4] = {0.f, 0.f, 0.f, 0.f};
  for (int s = 0; s < SY; ++s) {
    float p0 = s_sc[0][s], p1 = s_sc[1][s];
    const float* yr = yb + (size_t)s * DIM;
#pragma unroll
    for (int i = 0; i < 4; ++i) {
      float v = yr[tid + i * 256];
      a0[i] += p0 * v;
      a1[i] += p1 * v;
    }
  }
  float* tb = tokens + (size_t)b * NTOK * DIM;
#pragma unroll
  for (int i = 0; i < 4; ++i) {
    tb[tid + i * 256] = s_lat[0][tid + i * 256] + a0[i];
    tb[DIM + tid + i * 256] = s_lat[1][tid + i * 256] + a1[i];
  }
}

// gate != 0 slow path only: xp = x + softmax(x.tok)*tok*gate, into d_out.
__global__ __launch_bounds__(256) void xprime_kernel(const float* __restrict__ x,
                                                     const float* __restrict__ gate,
                                                     const float* __restrict__ tokens,
                                                     float* __restrict__ xp) {
  float g = gate[0];
  if (g == 0.0f) return;
  __shared__ float s_tok[NTOK][DIM];
  __shared__ float s_c[BM][2];
  int tid = threadIdx.x, w = tid >> 6, lane = tid & 63;
  size_t m0 = (size_t)blockIdx.x * BM;
  int b = (int)(m0 / SX);
  const float* xb = x + m0 * DIM;
  const float* tokb = tokens + (size_t)b * NTOK * DIM;
  for (int i = tid; i < NTOK * DIM; i += 256) ((float*)s_tok)[i] = tokb[i];
  __syncthreads();
  for (int i = 0; i < 16; ++i) {
    int r = w * 16 + i;
    const float* xrow = xb + (size_t)r * DIM;
    float d0 = 0.f, d1 = 0.f;
#pragma unroll
    for (int c = 0; c < 4; ++c) {
      f32x4 v = *(const f32x4*)(xrow + lane * 4 + c * 256);
      f32x4 t0 = *(const f32x4*)(&s_tok[0][lane * 4 + c * 256]);
      f32x4 t1 = *(const f32x4*)(&s_tok[1][lane * 4 + c * 256]);
      d0 += v[0] * t0[0] + v[1] * t0[1] + v[2] * t0[2] + v[3] * t0[3];
      d1 += v[0] * t1[0] + v[1] * t1[1] + v[2] * t1[2] + v[3] * t1[3];
    }
#pragma unroll
    for (int off = 32; off > 0; off >>= 1) {
      d0 += __shfl_xor(d0, off);
      d1 += __shfl_xor(d1, off);
    }
    if (lane == 0) {
      float mm = fmaxf(d0, d1);
      float e0 = expf(d0 - mm), e1 = expf(d1 - mm);
      float inv = g / (e0 + e1);
      s_c[r][0] = e0 * inv;
      s_c[r][1] = e1 * inv;
    }
  }
  __syncthreads();
  float* xpb = xp + m0 * DIM;
  for (int r = w * 16; r < w * 16 + 16; ++r) {
    float c0 = s_c[r][0], c1 = s_c[r][1];
#pragma unroll
    for (int c = 0; c < 4; ++c) {
      f32x4 v = *(const f32x4*)(xb + (size_t)r * DIM + lane * 4 + c * 256);
      f32x4 t0 = *(const f32x4*)(&s_tok[0][lane * 4 + c * 256]);
      f32x4 t1 = *(const f32x4*)(&s_tok[1][lane * 4 + c * 256]);
      f32x4 o;
#pragma unroll
      for (int j = 0; j < 4; ++j) o[j] = v[j] + c0 * t0[j] + c1 * t1[j];
      *(f32x4*)(xpb + (size_t)r * DIM + lane * 4 + c * 256) = o;
    }
  }
}

// Fused bottleneck: gll ring-4 + counted vmcnt(12) => 12KB/wave (96KB/CU)
// reads in flight across barriers. 2x4 wave grid (32 rows x 32 dn per wave)
// cuts LDS b128 reads 18->12 per wave-tile. 144KB LDS, 1 block/CU.
// (R16: verbatim revert to the best-verified R12 configuration, 146 us.)
__global__ __launch_bounds__(512) void main_kernel(const float* __restrict__ x,
                                                   const float* __restrict__ gate,
                                                   const float* __restrict__ xp,
                                                   const bf16* __restrict__ wdb,
                                                   const bf16* __restrict__ wub,
                                                   float* __restrict__ out) {
  // [0,65536): x ring (4 x 16KB fp32 64x64)
  // [65536,131072): wd ring (4 x 16KB bf16 128x64)
  // [131072,147456): Z tile (bf16 64x128)
  __shared__ __align__(16) char smem[147456];

  int tid = threadIdx.x, w = tid >> 6, l = tid & 63;
  int lq = l >> 4, lr = l & 15;
  int wr = w >> 2, wc = w & 3;  // 2 row-groups x 4 dn-groups
  size_t m0 = (size_t)blockIdx.x * BM;
  float g = gate[0];
  const float* xb = ((g != 0.f) ? xp : x) + m0 * DIM;

  // ---- pre-swizzled gll source pointers (per lane) ----
  const char* xsrc[2];
  const char* wsrc[2];
#pragma unroll
  for (int j = 0; j < 2; ++j) {
    int xr = w * 8 + j * 4 + (l >> 4);                      // x row staged
    int xcb = ((l & 15) * 16) ^ ((j * 4 + (l >> 4)) << 5);  // pre-swizzled byte
    xsrc[j] = (const char*)xb + (size_t)xr * (DIM * 4) + xcb;
    int wr_ = w * 16 + j * 8 + (l >> 3);                    // wd row staged
    int wcb = ((l & 7) * 16) ^ ((l >> 3) << 4);
    wsrc[j] = (const char*)wdb + (size_t)wr_ * (DIM * 2) + wcb;
  }

  f32x4 acc[2][2] = {};  // [mt][nf]

  auto STAGE = [&](int t) {
    int b = t & 3;
#pragma unroll
    for (int j = 0; j < 2; ++j)
      gll16(xsrc[j] + (size_t)t * (BK * 4),
            smem + b * 16384 + (w * 8 + j * 4) * 256);
#pragma unroll
    for (int j = 0; j < 2; ++j)
      gll16(wsrc[j] + (size_t)t * (BK * 2),
            smem + 65536 + b * 16384 + (w * 16 + j * 8) * 128);
  };

  auto COMP = [&](int b) {
    const char* xt = smem + b * 16384;
    const char* wt = smem + 65536 + b * 16384;
    __builtin_amdgcn_s_setprio(1);
#pragma unroll
    for (int kc = 0; kc < 2; ++kc) {
      bf16x8 wdf[2];
#pragma unroll
      for (int nf = 0; nf < 2; ++nf) {
        int dn = wc * 32 + nf * 16 + lr;
        wdf[nf] = *(const bf16x8*)(wt + dn * 128 +
                                   ((kc * 64 + lq * 16) ^ ((lr & 7) << 4)));
      }
#pragma unroll
      for (int mt = 0; mt < 2; ++mt) {
        int row = wr * 32 + mt * 16 + lr;
        int sz = (row & 7) << 5;
        int kb = kc * 128 + lq * 32;
        f32x4 a0 = *(const f32x4*)(xt + row * 256 + (kb ^ sz));
        f32x4 a1 = *(const f32x4*)(xt + row * 256 + ((kb + 16) ^ sz));
        bf16x8 xf;
#pragma unroll
        for (int jj = 0; jj < 4; ++jj) {
          xf[jj] = (bf16)a0[jj];
          xf[4 + jj] = (bf16)a1[jj];
        }
        acc[mt][0] = mfma16(wdf[0], xf, acc[mt][0]);  // D[dn][xrow]
        acc[mt][1] = mfma16(wdf[1], xf, acc[mt][1]);
      }
    }
    __builtin_amdgcn_s_setprio(0);
  };

  // ---- prologue: fill the ring ----
  STAGE(0);
  STAGE(1);
  STAGE(2);
  STAGE(3);

#pragma unroll
  for (int t = 0; t < NT; ++t) {
    if (t <= NT - 4) {
      asm volatile("s_waitcnt vmcnt(12)" ::: "memory");  // tile t landed
    } else if (t == NT - 3) {
      asm volatile("s_waitcnt vmcnt(8)" ::: "memory");
    } else if (t == NT - 2) {
      asm volatile("s_waitcnt vmcnt(4)" ::: "memory");
    } else {
      asm volatile("s_waitcnt vmcnt(0)" ::: "memory");
    }
    __builtin_amdgcn_sched_barrier(0);
    __builtin_amdgcn_s_barrier();      // tile t in LDS for ALL waves
    COMP(t & 3);
    __builtin_amdgcn_sched_barrier(0); // pin reads before release barrier
    __builtin_amdgcn_s_barrier();      // all waves done reading tile t
    if (t + 4 < NT) STAGE(t + 4);      // refill the buffer just released
  }

  // ---- ReLU -> bf16 Z into swizzled LDS ----
  char* zls = smem + 131072;
#pragma unroll
  for (int mt = 0; mt < 2; ++mt)
#pragma unroll
    for (int nf = 0; nf < 2; ++nf) {
      int xr = wr * 32 + mt * 16 + lr;
      int dn = wc * 32 + nf * 16 + lq * 4;
      bf16x4 pk;
#pragma unroll
      for (int r = 0; r < 4; ++r) pk[r] = (bf16)fmaxf(acc[mt][nf][r], 0.f);
      *(bf16x4*)(zls + xr * (DN * 2) + ((dn * 2) ^ ((xr & 7) << 4))) = pk;
    }
  __syncthreads();

  // ---- GEMM2: out^T-frag = mfma(Wu, Z); packed f32x4 stores ----
  bf16x8 zF[4][4];  // [kt][mt]
#pragma unroll
  for (int mt = 0; mt < 4; ++mt)
#pragma unroll
    for (int kt = 0; kt < 4; ++kt) {
      int xr = mt * 16 + lr;
      zF[kt][mt] = *(const bf16x8*)(zls + xr * (DN * 2) +
                                    (((kt * 32 + lq * 8) * 2) ^ ((xr & 7) << 4)));
    }

  float* ob = out + m0 * ODIM;
#pragma unroll 2
  for (int oc16 = 0; oc16 < 8; ++oc16) {
    int base = w * 128 + oc16 * 16;  // wave w owns out cols [w*128, +128)
    bf16x8 wu[4];
#pragma unroll
    for (int kt = 0; kt < 4; ++kt)
      wu[kt] = *(const bf16x8*)(wub + (size_t)(base + lr) * DN + kt * 32 + lq * 8);
    f32x4 a2[4] = {};
#pragma unroll
    for (int kt = 0; kt < 4; ++kt)
#pragma unroll
      for (int mt = 0; mt < 4; ++mt)
        a2[mt] = mfma16(wu[kt], zF[kt][mt], a2[mt]);
#pragma unroll
    for (int mt = 0; mt < 4; ++mt)
      *(f32x4*)(ob + (size_t)(mt * 16 + lr) * ODIM + base + lq * 4) = a2[mt];
  }
}

extern "C" void kernel_launch(void* const* d_in, const int* in_sizes, int n_in,
                              void* d_out, int out_size, void* d_ws, size_t ws_size,
                              hipStream_t stream) {
  const float* x = (const float*)d_in[0];
  const float* y = (const float*)d_in[1];
  const float* lat = (const float*)d_in[2];
  const float* gate = (const float*)d_in[3];
  const float* Wd = (const float*)d_in[4];
  const float* Wu = (const float*)d_in[5];
  float* out = (float*)d_out;
  char* ws = (char*)d_ws;

  float* tokens = (float*)ws;              // 262144 B
  bf16* wdb = (bf16*)(ws + 262144);        // 262144 B
  bf16* wub = (bf16*)(ws + 524288);        // 262144 B

  prep_kernel<<<(DN * DIM + 255) / 256, 256, 0, stream>>>(Wd, Wu, wdb, wub);
  tokens_kernel<<<B_N, 256, 0, stream>>>(y, lat, gate, tokens);
  // gate!=0 only: writes x' into d_out; main reads it back per block before
  // overwriting that block's region with out.
  xprime_kernel<<<(B_N * SX) / BM, 256, 0, stream>>>(x, gate, tokens, out);
  main_kernel<<<(B_N * SX) / BM, 512, 0, stream>>>(x, gate, out, wdb, wub, out);
}